// Round 2
// baseline (489.602 us; speedup 1.0000x reference)
//
#include <hip/hip_runtime.h>
#include <hip/hip_bf16.h>

// Problem constants
#define B_SZ  64
#define CIN   512
#define T_IN  2048
#define COUT  512
#define KW_   5
#define TOUT  2044

// Main kernel: 512 threads (8 waves), tile 128(co) x 512(t), BK=32.
// Each wave owns 128(co) x 64(t): acc[8][4] fragments of 16x16x32 bf16 MFMA.
// Double-buffered LDS + counted vmcnt (T3+T4 minimum-2-phase):
//   prologue stage(buf0); loop { stage(buf^1,next); s_waitcnt vmcnt(9);
//   s_barrier; compute(buf); s_barrier; }
// vmcnt(9): per wave 9 staging loads/iter (wave0: 10 incl. X tail; FIFO
// semantics make vmcnt(9) conservative there). Loads for tile i+1 stay in
// flight across the compute of tile i -- no vmcnt(0) drain in steady state.
// LDS bank-conflict XOR swizzle (chunk ^= (row>>1)&3) applied on BOTH the
// global_load_lds SOURCE and the ds_read address (rule #21); verified
// SQ_LDS_BANK_CONFLICT == 0.
#define BM    128
#define BN    512
#define BK    32
#define XROWS 516   // 512 t + 4 halo rows (kw window)

typedef __attribute__((ext_vector_type(8))) short   short8;
typedef __attribute__((ext_vector_type(4))) float   floatx4;

__device__ __forceinline__ unsigned short f2bf(float f) {
    unsigned int u = __builtin_bit_cast(unsigned int, f);
    u += 0x7fffu + ((u >> 16) & 1u);   // RNE
    return (unsigned short)(u >> 16);
}

__device__ __forceinline__ void gl_lds16(const void* g, void* l) {
    __builtin_amdgcn_global_load_lds(
        (const __attribute__((address_space(1))) unsigned int*)g,
        (__attribute__((address_space(3))) unsigned int*)l, 16, 0, 0);
}

// ---------------- pre-kernel 1: W fp32 [co][ci][kw] -> bf16 [kw][co][ci] ----
__global__ __launch_bounds__(256)
void wconv_kernel(const float* __restrict__ w, unsigned short* __restrict__ wbf) {
    int i = blockIdx.x * 256 + threadIdx.x;
    if (i < COUT * CIN * KW_) {
        int kw = i % KW_;
        int r  = i / KW_;
        int ci = r % CIN;
        int co = r / CIN;
        wbf[((size_t)kw * COUT + co) * CIN + ci] = f2bf(w[i]);
    }
}

// ---------------- pre-kernel 2: X fp32 [b][ci][t] -> bf16 [b][t][ci] --------
__global__ __launch_bounds__(256)
void xtrans_kernel(const float* __restrict__ x, unsigned short* __restrict__ xbf) {
    __shared__ float tile[64][68];
    const int t0  = blockIdx.x * 64;
    const int ci0 = blockIdx.y * 64;
    const int b   = blockIdx.z;
    const int tid = threadIdx.x;

    const float* xb = x + ((size_t)b * CIN + ci0) * T_IN + t0;
    const int cl = tid >> 4, fc = tid & 15;
#pragma unroll
    for (int p = 0; p < 4; ++p) {
        float4 v = *reinterpret_cast<const float4*>(xb + (size_t)(cl + p * 16) * T_IN + fc * 4);
        *reinterpret_cast<float4*>(&tile[cl + p * 16][fc * 4]) = v;
    }
    __syncthreads();

    const int tl = tid >> 2, cg = (tid & 3) * 16;
    unsigned short tmp[16];
#pragma unroll
    for (int j = 0; j < 16; ++j) tmp[j] = f2bf(tile[cg + j][tl]);
    unsigned short* dst = xbf + ((size_t)b * T_IN + t0 + tl) * CIN + ci0 + cg;
    *reinterpret_cast<short8*>(dst)     = *reinterpret_cast<short8*>(tmp);
    *reinterpret_cast<short8*>(dst + 8) = *reinterpret_cast<short8*>(tmp + 8);
}

// ------- main kernel: 128x512 block, 8 waves of 128x64, dbuf pipeline -------
__global__ __launch_bounds__(512, 2)
void tdl_conv_p2(const unsigned short* __restrict__ xbf,
                 const unsigned short* __restrict__ wbf,
                 const float* __restrict__ bias,
                 float* __restrict__ out)
{
    // Wl: 2 x [5][128][32] bf16 = 81920 B ; Xl: 2 x [516][32] bf16 = 66048 B
    // total 147968 B <= 160 KiB -> 1 block/CU (8 waves)
    __shared__ __align__(16) unsigned short Wl[2][KW_ * BM * BK];
    __shared__ __align__(16) unsigned short Xl[2][XROWS * BK];

    const int tid  = threadIdx.x;
    const int lane = tid & 63;
    const int wn   = tid >> 6;   // 0..7 (t); every wave owns all 128 co rows

    // XCD-aware swizzle (grid 1024 % 8 == 0 -> bijective)
    const int bid     = blockIdx.x;
    const int logical = ((bid & 7) << 7) | (bid >> 3);
    const int co_t = logical & 3;
    const int t_t  = (logical >> 2) & 3;
    const int b    = logical >> 4;

    const int co0 = co_t * BM;
    const int t0  = t_t * BN;

    const unsigned short* xb = xbf + (size_t)b * T_IN * CIN;

    floatx4 acc[8][4];
#pragma unroll
    for (int m = 0; m < 8; ++m)
#pragma unroll
        for (int n = 0; n < 4; ++n)
            acc[m][n] = (floatx4)(0.0f);

    const int arow = lane & 15;
    const int c0   = lane >> 4;                       // logical 16B chunk
    const int aswz = ((c0 ^ ((arow >> 1) & 3)) << 3); // W read swizzle (elems)

    // ---- staging: W 2560 chunks (5/thread), X 2064 chunks (4/thread + 16 tail)
    auto stage = [&](int sel, int ci0) {
#pragma unroll
        for (int it = 0; it < 5; ++it) {
            const int e  = tid + it * 512;
            const int kw = e >> 9;
            const int r  = e & 511;
            const int co = r >> 2;
            const int c8 = (((r & 3) ^ ((co >> 1) & 3)) << 3);
            gl_lds16(wbf + ((size_t)(kw * COUT + co0 + co)) * CIN + ci0 + c8,
                     &Wl[sel][e * 8]);
        }
#pragma unroll
        for (int it = 0; it < 4; ++it) {
            const int e  = tid + it * 512;
            const int t  = e >> 2;
            const int c8 = (((e & 3) ^ ((t >> 1) & 3)) << 3);
            gl_lds16(xb + (size_t)(t0 + t) * CIN + ci0 + c8, &Xl[sel][e * 8]);
        }
        if (tid < 16) {
            const int e  = 2048 + tid;
            const int t  = e >> 2;   // 512..515
            const int c8 = (((e & 3) ^ ((t >> 1) & 3)) << 3);
            int ts = t0 + t; if (ts > T_IN - 1) ts = T_IN - 1;  // feeds masked cols only
            gl_lds16(xb + (size_t)ts * CIN + ci0 + c8, &Xl[sel][e * 8]);
        }
    };

    auto compute = [&](int sel) {
#pragma unroll
        for (int kw = 0; kw < KW_; ++kw) {
            // X read swizzle: row = wn*64+n*16+arow+kw -> (row>>1)&3 = ((arow+kw)>>1)&3
            const int bswz = ((c0 ^ (((arow + kw) >> 1) & 3)) << 3);
            short8 af[8], bfr[4];
#pragma unroll
            for (int m = 0; m < 8; ++m)
                af[m] = *reinterpret_cast<const short8*>(
                    &Wl[sel][(kw * BM + m * 16 + arow) * BK + aswz]);
#pragma unroll
            for (int n = 0; n < 4; ++n)
                bfr[n] = *reinterpret_cast<const short8*>(
                    &Xl[sel][(wn * 64 + n * 16 + arow + kw) * BK + bswz]);
            __builtin_amdgcn_s_setprio(1);
#pragma unroll
            for (int m = 0; m < 8; ++m)
#pragma unroll
                for (int n = 0; n < 4; ++n)
                    acc[m][n] = __builtin_amdgcn_mfma_f32_16x16x32_bf16(
                        af[m], bfr[n], acc[m][n], 0, 0, 0);
            __builtin_amdgcn_s_setprio(0);
        }
    };

    // ---- pipelined K-loop: 16 ci-tiles, 2x unrolled for static buffer sel ----
    stage(0, 0);
#pragma unroll 1
    for (int i = 0; i < 16; i += 2) {
        // even half: prefetch tile i+1 into buf1, compute tile i from buf0
        stage(1, (i + 1) * BK);
        asm volatile("s_waitcnt vmcnt(9)" ::: "memory");   // tile-i loads landed
        __builtin_amdgcn_sched_barrier(0);
        __builtin_amdgcn_s_barrier();
        __builtin_amdgcn_sched_barrier(0);
        compute(0);
        __builtin_amdgcn_s_barrier();                      // buf0 reads done
        __builtin_amdgcn_sched_barrier(0);

        // odd half: prefetch tile i+2 into buf0, compute tile i+1 from buf1
        if (i + 2 < 16) {
            stage(0, (i + 2) * BK);
            asm volatile("s_waitcnt vmcnt(9)" ::: "memory");
        } else {
            asm volatile("s_waitcnt vmcnt(0)" ::: "memory");
        }
        __builtin_amdgcn_sched_barrier(0);
        __builtin_amdgcn_s_barrier();
        __builtin_amdgcn_sched_barrier(0);
        compute(1);
        __builtin_amdgcn_s_barrier();                      // buf1 reads done
        __builtin_amdgcn_sched_barrier(0);
    }

    // ---- epilogue: D layout col = lane&15 (t), row = (lane>>4)*4 + r (co)
    const int colb = wn * 64 + (lane & 15);
    const int rowb = (lane >> 4) * 4;
    float* outp = out + ((size_t)b * COUT + co0) * TOUT + t0;
#pragma unroll
    for (int m = 0; m < 8; ++m) {
        const int row0 = rowb + m * 16;
        float bv[4];
#pragma unroll
        for (int r = 0; r < 4; ++r) bv[r] = bias[co0 + row0 + r];
#pragma unroll
        for (int n = 0; n < 4; ++n) {
            const int col = colb + n * 16;
            if (t0 + col < TOUT) {
#pragma unroll
                for (int r = 0; r < 4; ++r)
                    outp[(size_t)(row0 + r) * TOUT + col] = acc[m][n][r] + bv[r];
            }
        }
    }
}

// ---------------- fallback (round-1 kernel, used if ws too small) -----------
#define PAD   40
__global__ __launch_bounds__(256, 2)
void tdl_conv_mfma(const float* __restrict__ x,
                   const float* __restrict__ w,
                   const float* __restrict__ bias,
                   float* __restrict__ out)
{
    __shared__ __align__(16) unsigned short Wlds[KW_][BM][PAD];
    __shared__ __align__(16) unsigned short Xlds[BM + 4][PAD];

    const int tid  = threadIdx.x;
    const int lane = tid & 63;
    const int wid  = tid >> 6;
    const int wm   = wid >> 1;
    const int wn   = wid & 1;

    const int bid  = blockIdx.x;
    const int co_t = bid & 3;
    const int t_t  = (bid >> 2) & 15;
    const int b    = bid >> 6;

    const int co0 = co_t * BM;
    const int t0  = t_t * BM;

    floatx4 acc[4][4];
#pragma unroll
    for (int m = 0; m < 4; ++m)
#pragma unroll
        for (int n = 0; n < 4; ++n)
            acc[m][n] = (floatx4)(0.0f);

    const float* xb = x + (size_t)b * CIN * T_IN;
    const int arow = lane & 15;
    const int k8   = (lane >> 4) * 8;

    for (int ci0 = 0; ci0 < CIN; ci0 += BK) {
        for (int e = tid; e < BK * 33; e += 256) {
            const int ci = e / 33;
            const int q  = e - ci * 33;
            const int tt = q * 4;
            const int tg = t0 + tt;
            float4 v = make_float4(0.f, 0.f, 0.f, 0.f);
            if (tg < T_IN)
                v = *reinterpret_cast<const float4*>(xb + (size_t)(ci0 + ci) * T_IN + tg);
            Xlds[tt + 0][ci] = f2bf(v.x);
            Xlds[tt + 1][ci] = f2bf(v.y);
            Xlds[tt + 2][ci] = f2bf(v.z);
            Xlds[tt + 3][ci] = f2bf(v.w);
        }
        for (int e = tid; e < BM * 40; e += 256) {
            const int co = e / 40;
            const int q  = e - co * 40;
            const float4 v = *reinterpret_cast<const float4*>(
                w + (size_t)(co0 + co) * (CIN * KW_) + ci0 * KW_ + q * 4);
            const int m0 = q * 4;
            Wlds[(m0    ) % 5][co][(m0    ) / 5] = f2bf(v.x);
            Wlds[(m0 + 1) % 5][co][(m0 + 1) / 5] = f2bf(v.y);
            Wlds[(m0 + 2) % 5][co][(m0 + 2) / 5] = f2bf(v.z);
            Wlds[(m0 + 3) % 5][co][(m0 + 3) / 5] = f2bf(v.w);
        }
        __syncthreads();
#pragma unroll
        for (int kw = 0; kw < KW_; ++kw) {
            short8 afrag[4], bfrag[4];
#pragma unroll
            for (int m = 0; m < 4; ++m)
                afrag[m] = *reinterpret_cast<const short8*>(
                    &Wlds[kw][wm * 64 + m * 16 + arow][k8]);
#pragma unroll
            for (int n = 0; n < 4; ++n)
                bfrag[n] = *reinterpret_cast<const short8*>(
                    &Xlds[wn * 64 + n * 16 + arow + kw][k8]);
#pragma unroll
            for (int m = 0; m < 4; ++m)
#pragma unroll
                for (int n = 0; n < 4; ++n)
                    acc[m][n] = __builtin_amdgcn_mfma_f32_16x16x32_bf16(
                        afrag[m], bfrag[n], acc[m][n], 0, 0, 0);
        }
        __syncthreads();
    }

    const int colb = wn * 64 + (lane & 15);
    const int rowb = wm * 64 + (lane >> 4) * 4;
    float* outp = out + ((size_t)b * COUT + co0) * TOUT + t0;
#pragma unroll
    for (int m = 0; m < 4; ++m) {
        const int row0 = rowb + m * 16;
        float bv[4];
#pragma unroll
        for (int r = 0; r < 4; ++r) bv[r] = bias[co0 + row0 + r];
#pragma unroll
        for (int n = 0; n < 4; ++n) {
            const int col = colb + n * 16;
            if (t0 + col < TOUT) {
#pragma unroll
                for (int r = 0; r < 4; ++r)
                    outp[(size_t)(row0 + r) * TOUT + col] = acc[m][n][r] + bv[r];
            }
        }
    }
}

extern "C" void kernel_launch(void* const* d_in, const int* in_sizes, int n_in,
                              void* d_out, int out_size, void* d_ws, size_t ws_size,
                              hipStream_t stream) {
    const float* x    = (const float*)d_in[0];
    const float* w    = (const float*)d_in[1];
    const float* bias = (const float*)d_in[2];
    float* out        = (float*)d_out;

    const size_t xbf_elems = (size_t)B_SZ * T_IN * CIN;
    const size_t wbf_elems = (size_t)KW_ * COUT * CIN;
    const size_t need = (xbf_elems + wbf_elems) * sizeof(unsigned short);

    if (ws_size >= need) {
        unsigned short* xbf = (unsigned short*)d_ws;
        unsigned short* wbf = xbf + xbf_elems;

        wconv_kernel<<<(COUT * CIN * KW_ + 255) / 256, 256, 0, stream>>>(w, wbf);
        dim3 tg(T_IN / 64, CIN / 64, B_SZ);
        xtrans_kernel<<<tg, 256, 0, stream>>>(x, xbf);
        // grid: 4 co-tiles * 4 t-tiles * 64 batches = 1024 blocks
        tdl_conv_p2<<<4 * 4 * B_SZ, 512, 0, stream>>>(xbf, wbf, bias, out);
    } else {
        tdl_conv_mfma<<<4 * 16 * B_SZ, 256, 0, stream>>>(x, w, bias, out);
    }
}

// Round 3
// 458.512 us; speedup vs baseline: 1.0678x; 1.0678x over previous
//
#include <hip/hip_runtime.h>
#include <hip/hip_bf16.h>

// Problem constants
#define B_SZ  64
#define CIN   512
#define T_IN  2048
#define COUT  512
#define KW_   5
#define TOUT  2044

// Main kernel: 512 threads (8 waves), tile 128(co) x 512(t), BK=32.
// Each wave owns 128(co) x 64(t): acc[8][4] fragments of 16x16x32 bf16 MFMA.
// Double-buffered LDS + counted vmcnt (T3+T4 minimum-2-phase):
//   prologue stage(buf0); loop { stage(buf^1,next); s_waitcnt vmcnt(9);
//   s_barrier; compute(buf); s_barrier; }
// vmcnt(9): per wave 9 staging loads/iter (wave0: 10 incl. X tail; FIFO
// semantics make vmcnt(9) conservative there).
//
// REG BUDGET (round-2 post-mortem): launch_bounds(512,2) => 8 waves/CU =>
// 256 unified regs/wave. acc = 128 AGPR, so arch VGPRs must fit 128.
// Round 2 spilled ~10 regs/iter (WRITE_SIZE 265->590 MB, VGPR pinned at 128).
// Fix: compute() processes the 8 m-fragments in two halves of 4 -> peak
// live fragments 48 -> 32 regs (bfr[4]=16 + af[4]=16). No other change.
//
// LDS bank-conflict XOR swizzle (chunk ^= (row>>1)&3) applied on BOTH the
// global_load_lds SOURCE and the ds_read address (rule #21); verified
// SQ_LDS_BANK_CONFLICT == 0.
#define BM    128
#define BN    512
#define BK    32
#define XROWS 516   // 512 t + 4 halo rows (kw window)

typedef __attribute__((ext_vector_type(8))) short   short8;
typedef __attribute__((ext_vector_type(4))) float   floatx4;

__device__ __forceinline__ unsigned short f2bf(float f) {
    unsigned int u = __builtin_bit_cast(unsigned int, f);
    u += 0x7fffu + ((u >> 16) & 1u);   // RNE
    return (unsigned short)(u >> 16);
}

__device__ __forceinline__ void gl_lds16(const void* g, void* l) {
    __builtin_amdgcn_global_load_lds(
        (const __attribute__((address_space(1))) unsigned int*)g,
        (__attribute__((address_space(3))) unsigned int*)l, 16, 0, 0);
}

// ---------------- pre-kernel 1: W fp32 [co][ci][kw] -> bf16 [kw][co][ci] ----
__global__ __launch_bounds__(256)
void wconv_kernel(const float* __restrict__ w, unsigned short* __restrict__ wbf) {
    int i = blockIdx.x * 256 + threadIdx.x;
    if (i < COUT * CIN * KW_) {
        int kw = i % KW_;
        int r  = i / KW_;
        int ci = r % CIN;
        int co = r / CIN;
        wbf[((size_t)kw * COUT + co) * CIN + ci] = f2bf(w[i]);
    }
}

// ---------------- pre-kernel 2: X fp32 [b][ci][t] -> bf16 [b][t][ci] --------
__global__ __launch_bounds__(256)
void xtrans_kernel(const float* __restrict__ x, unsigned short* __restrict__ xbf) {
    __shared__ float tile[64][68];
    const int t0  = blockIdx.x * 64;
    const int ci0 = blockIdx.y * 64;
    const int b   = blockIdx.z;
    const int tid = threadIdx.x;

    const float* xb = x + ((size_t)b * CIN + ci0) * T_IN + t0;
    const int cl = tid >> 4, fc = tid & 15;
#pragma unroll
    for (int p = 0; p < 4; ++p) {
        float4 v = *reinterpret_cast<const float4*>(xb + (size_t)(cl + p * 16) * T_IN + fc * 4);
        *reinterpret_cast<float4*>(&tile[cl + p * 16][fc * 4]) = v;
    }
    __syncthreads();

    const int tl = tid >> 2, cg = (tid & 3) * 16;
    unsigned short tmp[16];
#pragma unroll
    for (int j = 0; j < 16; ++j) tmp[j] = f2bf(tile[cg + j][tl]);
    unsigned short* dst = xbf + ((size_t)b * T_IN + t0 + tl) * CIN + ci0 + cg;
    *reinterpret_cast<short8*>(dst)     = *reinterpret_cast<short8*>(tmp);
    *reinterpret_cast<short8*>(dst + 8) = *reinterpret_cast<short8*>(tmp + 8);
}

// ------- main kernel: 128x512 block, 8 waves of 128x64, dbuf pipeline -------
__global__ __launch_bounds__(512, 2)
void tdl_conv_p2(const unsigned short* __restrict__ xbf,
                 const unsigned short* __restrict__ wbf,
                 const float* __restrict__ bias,
                 float* __restrict__ out)
{
    // Wl: 2 x [5][128][32] bf16 = 81920 B ; Xl: 2 x [516][32] bf16 = 66048 B
    // total 147968 B <= 160 KiB -> 1 block/CU (8 waves)
    __shared__ __align__(16) unsigned short Wl[2][KW_ * BM * BK];
    __shared__ __align__(16) unsigned short Xl[2][XROWS * BK];

    const int tid  = threadIdx.x;
    const int lane = tid & 63;
    const int wn   = tid >> 6;   // 0..7 (t); every wave owns all 128 co rows

    // XCD-aware swizzle (grid 1024 % 8 == 0 -> bijective)
    const int bid     = blockIdx.x;
    const int logical = ((bid & 7) << 7) | (bid >> 3);
    const int co_t = logical & 3;
    const int t_t  = (logical >> 2) & 3;
    const int b    = logical >> 4;

    const int co0 = co_t * BM;
    const int t0  = t_t * BN;

    const unsigned short* xb = xbf + (size_t)b * T_IN * CIN;

    floatx4 acc[8][4];
#pragma unroll
    for (int m = 0; m < 8; ++m)
#pragma unroll
        for (int n = 0; n < 4; ++n)
            acc[m][n] = (floatx4)(0.0f);

    const int arow = lane & 15;
    const int c0   = lane >> 4;                       // logical 16B chunk
    const int aswz = ((c0 ^ ((arow >> 1) & 3)) << 3); // W read swizzle (elems)

    // ---- staging: W 2560 chunks (5/thread), X 2064 chunks (4/thread + 16 tail)
    auto stage = [&](int sel, int ci0) {
#pragma unroll
        for (int it = 0; it < 5; ++it) {
            const int e  = tid + it * 512;
            const int kw = e >> 9;
            const int r  = e & 511;
            const int co = r >> 2;
            const int c8 = (((r & 3) ^ ((co >> 1) & 3)) << 3);
            gl_lds16(wbf + ((size_t)(kw * COUT + co0 + co)) * CIN + ci0 + c8,
                     &Wl[sel][e * 8]);
        }
#pragma unroll
        for (int it = 0; it < 4; ++it) {
            const int e  = tid + it * 512;
            const int t  = e >> 2;
            const int c8 = (((e & 3) ^ ((t >> 1) & 3)) << 3);
            gl_lds16(xb + (size_t)(t0 + t) * CIN + ci0 + c8, &Xl[sel][e * 8]);
        }
        if (tid < 16) {
            const int e  = 2048 + tid;
            const int t  = e >> 2;   // 512..515
            const int c8 = (((e & 3) ^ ((t >> 1) & 3)) << 3);
            int ts = t0 + t; if (ts > T_IN - 1) ts = T_IN - 1;  // feeds masked cols only
            gl_lds16(xb + (size_t)ts * CIN + ci0 + c8, &Xl[sel][e * 8]);
        }
    };

    // compute: m-fragments in two halves of 4 to keep peak live fragment
    // regs at 32 (bfr[4] + af[4]) -- arch VGPRs must fit 128 (see header).
    auto compute = [&](int sel) {
#pragma unroll
        for (int kw = 0; kw < KW_; ++kw) {
            // X read swizzle: row = wn*64+n*16+arow+kw -> (row>>1)&3 = ((arow+kw)>>1)&3
            const int bswz = ((c0 ^ (((arow + kw) >> 1) & 3)) << 3);
            short8 bfr[4];
#pragma unroll
            for (int n = 0; n < 4; ++n)
                bfr[n] = *reinterpret_cast<const short8*>(
                    &Xl[sel][(wn * 64 + n * 16 + arow + kw) * BK + bswz]);
#pragma unroll
            for (int mh = 0; mh < 2; ++mh) {
                short8 af[4];
#pragma unroll
                for (int m4 = 0; m4 < 4; ++m4)
                    af[m4] = *reinterpret_cast<const short8*>(
                        &Wl[sel][(kw * BM + (mh * 4 + m4) * 16 + arow) * BK + aswz]);
                __builtin_amdgcn_s_setprio(1);
#pragma unroll
                for (int m4 = 0; m4 < 4; ++m4)
#pragma unroll
                    for (int n = 0; n < 4; ++n)
                        acc[mh * 4 + m4][n] = __builtin_amdgcn_mfma_f32_16x16x32_bf16(
                            af[m4], bfr[n], acc[mh * 4 + m4][n], 0, 0, 0);
                __builtin_amdgcn_s_setprio(0);
            }
        }
    };

    // ---- pipelined K-loop: 16 ci-tiles, 2x unrolled for static buffer sel ----
    stage(0, 0);
#pragma unroll 1
    for (int i = 0; i < 16; i += 2) {
        // even half: prefetch tile i+1 into buf1, compute tile i from buf0
        stage(1, (i + 1) * BK);
        asm volatile("s_waitcnt vmcnt(9)" ::: "memory");   // tile-i loads landed
        __builtin_amdgcn_sched_barrier(0);
        __builtin_amdgcn_s_barrier();
        __builtin_amdgcn_sched_barrier(0);
        compute(0);
        __builtin_amdgcn_s_barrier();                      // buf0 reads done
        __builtin_amdgcn_sched_barrier(0);

        // odd half: prefetch tile i+2 into buf0, compute tile i+1 from buf1
        if (i + 2 < 16) {
            stage(0, (i + 2) * BK);
            asm volatile("s_waitcnt vmcnt(9)" ::: "memory");
        } else {
            asm volatile("s_waitcnt vmcnt(0)" ::: "memory");
        }
        __builtin_amdgcn_sched_barrier(0);
        __builtin_amdgcn_s_barrier();
        __builtin_amdgcn_sched_barrier(0);
        compute(1);
        __builtin_amdgcn_s_barrier();                      // buf1 reads done
        __builtin_amdgcn_sched_barrier(0);
    }

    // ---- epilogue: D layout col = lane&15 (t), row = (lane>>4)*4 + r (co)
    const int colb = wn * 64 + (lane & 15);
    const int rowb = (lane >> 4) * 4;
    float* outp = out + ((size_t)b * COUT + co0) * TOUT + t0;
#pragma unroll
    for (int m = 0; m < 8; ++m) {
        const int row0 = rowb + m * 16;
        float bv[4];
#pragma unroll
        for (int r = 0; r < 4; ++r) bv[r] = bias[co0 + row0 + r];
#pragma unroll
        for (int n = 0; n < 4; ++n) {
            const int col = colb + n * 16;
            if (t0 + col < TOUT) {
#pragma unroll
                for (int r = 0; r < 4; ++r)
                    outp[(size_t)(row0 + r) * TOUT + col] = acc[m][n][r] + bv[r];
            }
        }
    }
}

// ---------------- fallback (round-1 kernel, used if ws too small) -----------
#define PAD   40
__global__ __launch_bounds__(256, 2)
void tdl_conv_mfma(const float* __restrict__ x,
                   const float* __restrict__ w,
                   const float* __restrict__ bias,
                   float* __restrict__ out)
{
    __shared__ __align__(16) unsigned short Wlds[KW_][BM][PAD];
    __shared__ __align__(16) unsigned short Xlds[BM + 4][PAD];

    const int tid  = threadIdx.x;
    const int lane = tid & 63;
    const int wid  = tid >> 6;
    const int wm   = wid >> 1;
    const int wn   = wid & 1;

    const int bid  = blockIdx.x;
    const int co_t = bid & 3;
    const int t_t  = (bid >> 2) & 15;
    const int b    = bid >> 6;

    const int co0 = co_t * BM;
    const int t0  = t_t * BM;

    floatx4 acc[4][4];
#pragma unroll
    for (int m = 0; m < 4; ++m)
#pragma unroll
        for (int n = 0; n < 4; ++n)
            acc[m][n] = (floatx4)(0.0f);

    const float* xb = x + (size_t)b * CIN * T_IN;
    const int arow = lane & 15;
    const int k8   = (lane >> 4) * 8;

    for (int ci0 = 0; ci0 < CIN; ci0 += BK) {
        for (int e = tid; e < BK * 33; e += 256) {
            const int ci = e / 33;
            const int q  = e - ci * 33;
            const int tt = q * 4;
            const int tg = t0 + tt;
            float4 v = make_float4(0.f, 0.f, 0.f, 0.f);
            if (tg < T_IN)
                v = *reinterpret_cast<const float4*>(xb + (size_t)(ci0 + ci) * T_IN + tg);
            Xlds[tt + 0][ci] = f2bf(v.x);
            Xlds[tt + 1][ci] = f2bf(v.y);
            Xlds[tt + 2][ci] = f2bf(v.z);
            Xlds[tt + 3][ci] = f2bf(v.w);
        }
        for (int e = tid; e < BM * 40; e += 256) {
            const int co = e / 40;
            const int q  = e - co * 40;
            const float4 v = *reinterpret_cast<const float4*>(
                w + (size_t)(co0 + co) * (CIN * KW_) + ci0 * KW_ + q * 4);
            const int m0 = q * 4;
            Wlds[(m0    ) % 5][co][(m0    ) / 5] = f2bf(v.x);
            Wlds[(m0 + 1) % 5][co][(m0 + 1) / 5] = f2bf(v.y);
            Wlds[(m0 + 2) % 5][co][(m0 + 2) / 5] = f2bf(v.z);
            Wlds[(m0 + 3) % 5][co][(m0 + 3) / 5] = f2bf(v.w);
        }
        __syncthreads();
#pragma unroll
        for (int kw = 0; kw < KW_; ++kw) {
            short8 afrag[4], bfrag[4];
#pragma unroll
            for (int m = 0; m < 4; ++m)
                afrag[m] = *reinterpret_cast<const short8*>(
                    &Wlds[kw][wm * 64 + m * 16 + arow][k8]);
#pragma unroll
            for (int n = 0; n < 4; ++n)
                bfrag[n] = *reinterpret_cast<const short8*>(
                    &Xlds[wn * 64 + n * 16 + arow + kw][k8]);
#pragma unroll
            for (int m = 0; m < 4; ++m)
#pragma unroll
                for (int n = 0; n < 4; ++n)
                    acc[m][n] = __builtin_amdgcn_mfma_f32_16x16x32_bf16(
                        afrag[m], bfrag[n], acc[m][n], 0, 0, 0);
        }
        __syncthreads();
    }

    const int colb = wn * 64 + (lane & 15);
    const int rowb = wm * 64 + (lane >> 4) * 4;
    float* outp = out + ((size_t)b * COUT + co0) * TOUT + t0;
#pragma unroll
    for (int m = 0; m < 4; ++m) {
        const int row0 = rowb + m * 16;
        float bv[4];
#pragma unroll
        for (int r = 0; r < 4; ++r) bv[r] = bias[co0 + row0 + r];
#pragma unroll
        for (int n = 0; n < 4; ++n) {
            const int col = colb + n * 16;
            if (t0 + col < TOUT) {
#pragma unroll
                for (int r = 0; r < 4; ++r)
                    outp[(size_t)(row0 + r) * TOUT + col] = acc[m][n][r] + bv[r];
            }
        }
    }
}

extern "C" void kernel_launch(void* const* d_in, const int* in_sizes, int n_in,
                              void* d_out, int out_size, void* d_ws, size_t ws_size,
                              hipStream_t stream) {
    const float* x    = (const float*)d_in[0];
    const float* w    = (const float*)d_in[1];
    const float* bias = (const float*)d_in[2];
    float* out        = (float*)d_out;

    const size_t xbf_elems = (size_t)B_SZ * T_IN * CIN;
    const size_t wbf_elems = (size_t)KW_ * COUT * CIN;
    const size_t need = (xbf_elems + wbf_elems) * sizeof(unsigned short);

    if (ws_size >= need) {
        unsigned short* xbf = (unsigned short*)d_ws;
        unsigned short* wbf = xbf + xbf_elems;

        wconv_kernel<<<(COUT * CIN * KW_ + 255) / 256, 256, 0, stream>>>(w, wbf);
        dim3 tg(T_IN / 64, CIN / 64, B_SZ);
        xtrans_kernel<<<tg, 256, 0, stream>>>(x, xbf);
        // grid: 4 co-tiles * 4 t-tiles * 64 batches = 1024 blocks
        tdl_conv_p2<<<4 * 4 * B_SZ, 512, 0, stream>>>(xbf, wbf, bias, out);
    } else {
        tdl_conv_mfma<<<4 * 16 * B_SZ, 256, 0, stream>>>(x, w, bias, out);
    }
}